// Round 22
// baseline (144.553 us; speedup 1.0000x reference)
//
#include <hip/hip_runtime.h>
#include <math.h>

typedef float v2f __attribute__((ext_vector_type(2)));

#define N_POINTS 32768
#define NUM_EMBED 8192
#define CH 64                                // chunks (fits 64-bit survivor mask)
#define CPC (NUM_EMBED / CH)                 // 128 candidates per chunk
#define PAIRS (CPC / 2)                      // 64 pairs per chunk
#define PPT 8                                // filter points per thread
#define RB 1024                              // resolve block threads (16 waves, 16 points)
#define RPB (RB / 64)                        // 16 points per resolve block
#define RGRID (N_POINTS / RPB)               // 2048 resolve blocks
#define CSTRIDE 4096                         // 64*64, channel stride in z [B,C,H,W]

// packed f32 ops forced via inline asm (per-half IEEE rn, bit-identical to scalar chain)
__device__ __forceinline__ v2f pk_mul(v2f a, v2f b) {
    v2f d; asm("v_pk_mul_f32 %0, %1, %2" : "=v"(d) : "v"(a), "v"(b)); return d;
}
__device__ __forceinline__ v2f pk_fma(v2f a, v2f b, v2f c) {
    v2f d; asm("v_pk_fma_f32 %0, %1, %2, %3" : "=v"(d) : "v"(a), "v"(b), "v"(c)); return d;
}

// order-preserving bijection float -> uint32 (total order == float <)
__device__ __forceinline__ unsigned int fkey(float f) {
    unsigned int b = __float_as_uint(f);
    return b ^ (0x80000000u | (unsigned int)((int)b >> 31));
}

// ---------------- kernel A (filter, prep fused): per (point, chunk) max of dot_j.
// Stages its chunk straight from E with in-register pair-interleave (float-exact copy,
// layout identical to the old Epk). dot chain = exact XLA bits (mul + ascending fma).
// Wave-uniform LDS reads: one b128 broadcast serves 64 lanes x 8 points.
__global__ __launch_bounds__(256) void vq_filter_kernel(
        const float* __restrict__ z, const float4* __restrict__ E,
        float* __restrict__ cmax) {
    __shared__ alignas(16) v2f sE[PAIRS * 4];   // 2 KB, pair-interleaved

    const int c = blockIdx.y;
    if (threadIdx.x < CPC) {                     // 128 threads: coalesced 2KB read of E
        float4 e = E[c * CPC + threadIdx.x];
        int p = threadIdx.x >> 1, h = threadIdx.x & 1;
        float* sf = (float*)sE;                  // sf[8p+2k+h] = E[2p+h][k]  (== Epk bits)
        sf[8 * p + 0 + h] = e.x;
        sf[8 * p + 2 + h] = e.y;
        sf[8 * p + 4 + h] = e.z;
        sf[8 * p + 6 + h] = e.w;
    }

    const int n0 = blockIdx.x * (256 * PPT) + threadIdx.x;

    v2f zv[PPT][4];
    #pragma unroll
    for (int p = 0; p < PPT; ++p) {
        int n = n0 + p * 256;
        int b = n >> 12, hw = n & 4095;
        const float* zp = z + b * 16384 + hw;
        zv[p][0] = (v2f){zp[0], zp[0]};
        zv[p][1] = (v2f){zp[CSTRIDE], zp[CSTRIDE]};
        zv[p][2] = (v2f){zp[2 * CSTRIDE], zp[2 * CSTRIDE]};
        zv[p][3] = (v2f){zp[3 * CSTRIDE], zp[3 * CSTRIDE]};
    }

    __syncthreads();

    float run[PPT];
    #pragma unroll
    for (int p = 0; p < PPT; ++p) run[p] = -__builtin_inff();

    const float4* sE4 = (const float4*)sE;
    #pragma unroll 2
    for (int t = 0; t < PAIRS; ++t) {
        // uniform LDS reads -> hardware broadcast, no bank conflicts
        float4 E01 = sE4[2 * t];       // {e0.lo,e0.hi, e1.lo,e1.hi}
        float4 E23 = sE4[2 * t + 1];   // {e2.lo,e2.hi, e3.lo,e3.hi}
        v2f e0 = {E01.x, E01.y};
        v2f e1 = {E01.z, E01.w};
        v2f e2 = {E23.x, E23.y};
        v2f e3 = {E23.z, E23.w};
        #pragma unroll
        for (int p = 0; p < PPT; ++p) {
            v2f dot = pk_mul(zv[p][0], e0);       // z0*e0       (rn)
            dot = pk_fma(zv[p][1], e1, dot);      // ascending-k fma chain
            dot = pk_fma(zv[p][2], e2, dot);
            dot = pk_fma(zv[p][3], e3, dot);
            run[p] = fmaxf(fmaxf(dot.x, dot.y), run[p]);  // exact selection (v_max3)
        }
    }

    #pragma unroll
    for (int p = 0; p < PPT; ++p)
        cmax[(size_t)c * N_POINTS + n0 + p * 256] = run[p];   // coalesced 256B/wave
}

// ---------------- kernel B (resolve + tail loss): 16 waves / 16 points per block.
// Phase 1: full-line tile load of cmax into padded LDS. Phase 2 per wave (r11-proven):
// shfl gmax; thr = gmax - (2u + 1e-7) [r9 window]; ballot survivors; coalesced
// EXACT-chain rescan; 64-bit key min = first-index argmin. Tail: last-arriving block
// (agent-scope counter) does a fixed-order deterministic reduce of all partials.
__global__ __launch_bounds__(RB) void vq_resolve_kernel(
        const float* __restrict__ z, const float4* __restrict__ E,
        const float* __restrict__ cmax,
        float* __restrict__ out, double* __restrict__ partial,
        unsigned int* __restrict__ done) {
    __shared__ float sCm[CH][RPB + 1];           // 64 x 17 floats: odd stride, <=2-way
    __shared__ double sdata[RPB];
    __shared__ double sred[RB];                  // 8 KB tail reduce
    __shared__ int sLast;
    const int lane = threadIdx.x & 63;
    const int wid = threadIdx.x >> 6;
    const int n0 = blockIdx.x * RPB;
    const int n = n0 + wid;

    // ---- phase 1: cooperative tile load, line-granular (64B per 16 threads)
    {
        int t = threadIdx.x;
        sCm[t >> 4][t & 15] = cmax[(size_t)(t >> 4) * N_POINTS + n0 + (t & 15)];
    }

    const int b = n >> 12;
    const int hw = n & 4095;
    const float* zp = z + b * 16384 + hw;
    float z0 = zp[0];
    float z1 = zp[CSTRIDE];
    float z2 = zp[2 * CSTRIDE];
    float z3 = zp[3 * CSTRIDE];
    float zz = __fmul_rn(z0, z0);
    zz = __fadd_rn(zz, __fmul_rn(z1, z1));
    zz = __fadd_rn(zz, __fmul_rn(z2, z2));
    zz = __fadd_rn(zz, __fmul_rn(z3, z3));

    __syncthreads();

    // lane c holds chunk c's max-dot; wave max-reduce
    float cm = sCm[lane][wid];
    float gmax = cm;
    #pragma unroll
    for (int off = 32; off; off >>= 1)
        gmax = fmaxf(gmax, __shfl_xor(gmax, off));

    // conservative bound (proven round 9): survivors have dot >= gmax - (2u + 1e-7)
    float u = __fmul_rn(__fadd_rn(zz, 0.01f), 2.38418579e-07f);   // (zz+.01)*2^-22
    float thr = __fsub_rn(gmax, __fadd_rn(__fadd_rn(u, u), 1e-7f));
    unsigned long long mask = __ballot(cm >= thr);   // wave-uniform, >=1 bit set

    // exact rescan of surviving chunks (coalesced: lane -> j0+lane, j0+64+lane)
    unsigned long long bkey = ~0ull;
    while (mask) {
        int c = __builtin_ctzll(mask);
        mask &= mask - 1ull;
        int j0 = c * CPC + lane;
        #pragma unroll
        for (int h = 0; h < 2; ++h) {
            int j = j0 + h * 64;
            float4 e = E[j];
            float ee = __fmul_rn(e.x, e.x);
            ee = __fadd_rn(ee, __fmul_rn(e.y, e.y));
            ee = __fadd_rn(ee, __fmul_rn(e.z, e.z));
            ee = __fadd_rn(ee, __fmul_rn(e.w, e.w));
            float dot = __fmul_rn(z0, e.x);
            dot = __fmaf_rn(z1, e.y, dot);
            dot = __fmaf_rn(z2, e.z, dot);
            dot = __fmaf_rn(z3, e.w, dot);
            float d = __fmaf_rn(-2.0f, dot, __fadd_rn(zz, ee));
            // key: (orderable d) << 32 | j  -> min key = min d, tie -> min j (first index)
            unsigned long long key =
                ((unsigned long long)fkey(d) << 32) | (unsigned int)j;
            bkey = key < bkey ? key : bkey;
        }
    }
    #pragma unroll
    for (int off = 32; off; off >>= 1) {
        unsigned long long o = __shfl_xor(bkey, off);
        bkey = o < bkey ? o : bkey;
    }
    int besti = (int)(unsigned int)(bkey & 0xFFFFFFFFull);

    if (lane == 0) {
        float4 e = E[besti];
        float* op = out + b * 16384 + hw;
        float t0 = __fsub_rn(e.x, z0);
        float t1 = __fsub_rn(e.y, z1);
        float t2 = __fsub_rn(e.z, z2);
        float t3 = __fsub_rn(e.w, z3);
        op[0]           = __fadd_rn(z0, t0);     // straight-through: z + (z_q - z)
        op[CSTRIDE]     = __fadd_rn(z1, t1);
        op[2 * CSTRIDE] = __fadd_rn(z2, t2);
        op[3 * CSTRIDE] = __fadd_rn(z3, t3);
        out[131073 + n] = (float)besti;          // indices as float32 (exact)
        double ds = (double)__fmul_rn(t0, t0) + (double)__fmul_rn(t1, t1)
                  + (double)__fmul_rn(t2, t2) + (double)__fmul_rn(t3, t3);
        sdata[wid] = ds;
    }
    __syncthreads();

    // ---- tail: publish partial, last-arriving block reduces (fixed order = deterministic)
    if (threadIdx.x == 0) {
        double s = 0.0;
        #pragma unroll
        for (int w = 0; w < RPB; ++w) s += sdata[w];
        __hip_atomic_store(&partial[blockIdx.x], s, __ATOMIC_RELEASE,
                           __HIP_MEMORY_SCOPE_AGENT);
        unsigned int prev = __hip_atomic_fetch_add(done, 1u, __ATOMIC_ACQ_REL,
                                                   __HIP_MEMORY_SCOPE_AGENT);
        sLast = (prev == RGRID - 1);
    }
    __syncthreads();
    if (sLast) {                                 // block-uniform; no spin anywhere
        double s = __hip_atomic_load(&partial[threadIdx.x], __ATOMIC_RELAXED,
                                     __HIP_MEMORY_SCOPE_AGENT)
                 + __hip_atomic_load(&partial[threadIdx.x + RB], __ATOMIC_RELAXED,
                                     __HIP_MEMORY_SCOPE_AGENT);
        sred[threadIdx.x] = s;
        __syncthreads();
        #pragma unroll
        for (int st = RB / 2; st > 0; st >>= 1) {
            if (threadIdx.x < st) sred[threadIdx.x] += sred[threadIdx.x + st];
            __syncthreads();
        }
        if (threadIdx.x == 0) {
            float m = (float)(sred[0] / 131072.0);
            // loss = mean + BETA*mean (both means are numerically identical)
            out[131072] = __fadd_rn(m, __fmul_rn(0.25f, m));
        }
    }
}

extern "C" void kernel_launch(void* const* d_in, const int* in_sizes, int n_in,
                              void* d_out, int out_size, void* d_ws, size_t ws_size,
                              hipStream_t stream) {
    const float* z = (const float*)d_in[0];
    const float4* E = (const float4*)d_in[1];
    float* out = (float*)d_out;

    char* ws = (char*)d_ws;
    float* cmaxb = (float*)ws;                                // 8 MB, [c][n]
    double* partial = (double*)(ws + (size_t)CH * N_POINTS * 4);       // 16 KB
    unsigned int* done = (unsigned int*)(ws + (size_t)CH * N_POINTS * 4 + RGRID * 8);

    hipMemsetAsync(done, 0, 4, stream);          // graph-capturable reset of tail counter
    vq_filter_kernel<<<dim3(N_POINTS / (256 * PPT), CH), 256, 0, stream>>>(z, E, cmaxb);
    vq_resolve_kernel<<<RGRID, RB, 0, stream>>>(z, E, cmaxb, out, partial, done);
}

// Round 23
// 48.363 us; speedup vs baseline: 2.9889x; 2.9889x over previous
//
#include <hip/hip_runtime.h>
#include <math.h>

typedef float v2f __attribute__((ext_vector_type(2)));

#define N_POINTS 32768
#define NUM_EMBED 8192
#define CH 64                                // chunks (fits 64-bit survivor mask)
#define CPC (NUM_EMBED / CH)                 // 128 candidates per chunk
#define PAIRS (CPC / 2)                      // 64 pairs per chunk
#define PPT 8                                // filter points per thread
#define RB 1024                              // resolve block threads (16 waves, 16 points)
#define RPB (RB / 64)                        // 16 points per resolve block
#define RGRID (N_POINTS / RPB)               // 2048 resolve blocks
#define CSTRIDE 4096                         // 64*64, channel stride in z [B,C,H,W]

// packed f32 ops forced via inline asm (per-half IEEE rn, bit-identical to scalar chain)
__device__ __forceinline__ v2f pk_mul(v2f a, v2f b) {
    v2f d; asm("v_pk_mul_f32 %0, %1, %2" : "=v"(d) : "v"(a), "v"(b)); return d;
}
__device__ __forceinline__ v2f pk_fma(v2f a, v2f b, v2f c) {
    v2f d; asm("v_pk_fma_f32 %0, %1, %2, %3" : "=v"(d) : "v"(a), "v"(b), "v"(c)); return d;
}

// order-preserving bijection float -> uint32 (total order == float <)
__device__ __forceinline__ unsigned int fkey(float f) {
    unsigned int b = __float_as_uint(f);
    return b ^ (0x80000000u | (unsigned int)((int)b >> 31));
}

// ---------------- kernel A (filter, prep fused; r22-proven): per (point, chunk) dot-max.
// Stages its chunk straight from E with in-register pair-interleave (float-exact copy).
// dot chain = exact XLA bits (mul + ascending fma). Wave-uniform broadcast LDS reads.
__global__ __launch_bounds__(256) void vq_filter_kernel(
        const float* __restrict__ z, const float4* __restrict__ E,
        float* __restrict__ cmax) {
    __shared__ alignas(16) v2f sE[PAIRS * 4];   // 2 KB, pair-interleaved

    const int c = blockIdx.y;
    if (threadIdx.x < CPC) {                     // 128 threads: coalesced 2KB read of E
        float4 e = E[c * CPC + threadIdx.x];
        int p = threadIdx.x >> 1, h = threadIdx.x & 1;
        float* sf = (float*)sE;                  // sf[8p+2k+h] = E[2p+h][k]
        sf[8 * p + 0 + h] = e.x;
        sf[8 * p + 2 + h] = e.y;
        sf[8 * p + 4 + h] = e.z;
        sf[8 * p + 6 + h] = e.w;
    }

    const int n0 = blockIdx.x * (256 * PPT) + threadIdx.x;

    v2f zv[PPT][4];
    #pragma unroll
    for (int p = 0; p < PPT; ++p) {
        int n = n0 + p * 256;
        int b = n >> 12, hw = n & 4095;
        const float* zp = z + b * 16384 + hw;
        zv[p][0] = (v2f){zp[0], zp[0]};
        zv[p][1] = (v2f){zp[CSTRIDE], zp[CSTRIDE]};
        zv[p][2] = (v2f){zp[2 * CSTRIDE], zp[2 * CSTRIDE]};
        zv[p][3] = (v2f){zp[3 * CSTRIDE], zp[3 * CSTRIDE]};
    }

    __syncthreads();

    float run[PPT];
    #pragma unroll
    for (int p = 0; p < PPT; ++p) run[p] = -__builtin_inff();

    const float4* sE4 = (const float4*)sE;
    #pragma unroll 2
    for (int t = 0; t < PAIRS; ++t) {
        // uniform LDS reads -> hardware broadcast, no bank conflicts
        float4 E01 = sE4[2 * t];       // {e0.lo,e0.hi, e1.lo,e1.hi}
        float4 E23 = sE4[2 * t + 1];   // {e2.lo,e2.hi, e3.lo,e3.hi}
        v2f e0 = {E01.x, E01.y};
        v2f e1 = {E01.z, E01.w};
        v2f e2 = {E23.x, E23.y};
        v2f e3 = {E23.z, E23.w};
        #pragma unroll
        for (int p = 0; p < PPT; ++p) {
            v2f dot = pk_mul(zv[p][0], e0);       // z0*e0       (rn)
            dot = pk_fma(zv[p][1], e1, dot);      // ascending-k fma chain
            dot = pk_fma(zv[p][2], e2, dot);
            dot = pk_fma(zv[p][3], e3, dot);
            run[p] = fmaxf(fmaxf(dot.x, dot.y), run[p]);  // exact selection (v_max3)
        }
    }

    #pragma unroll
    for (int p = 0; p < PPT; ++p)
        cmax[(size_t)c * N_POINTS + n0 + p * 256] = run[p];   // coalesced 256B/wave
}

// ---------------- kernel B (resolve; r16-proven, NO atomics/tail): 16 waves / 16 points.
// Phase 1: full-line tile load of cmax into padded LDS. Phase 2 per wave:
// shfl gmax; thr = gmax - (2u + 1e-7) [r9 window]; ballot survivors; coalesced
// EXACT-chain rescan; 64-bit key min-reduce = exact first-index argmin.
__global__ __launch_bounds__(RB) void vq_resolve_kernel(
        const float* __restrict__ z, const float4* __restrict__ E,
        const float* __restrict__ cmax,
        float* __restrict__ out, double* __restrict__ partial) {
    __shared__ float sCm[CH][RPB + 1];           // 64 x 17 floats: odd stride, <=2-way
    __shared__ double sdata[RPB];
    const int lane = threadIdx.x & 63;
    const int wid = threadIdx.x >> 6;
    const int n0 = blockIdx.x * RPB;
    const int n = n0 + wid;

    // ---- phase 1: cooperative tile load, line-granular (64B per 16 threads)
    {
        int t = threadIdx.x;
        sCm[t >> 4][t & 15] = cmax[(size_t)(t >> 4) * N_POINTS + n0 + (t & 15)];
    }

    const int b = n >> 12;
    const int hw = n & 4095;
    const float* zp = z + b * 16384 + hw;
    float z0 = zp[0];
    float z1 = zp[CSTRIDE];
    float z2 = zp[2 * CSTRIDE];
    float z3 = zp[3 * CSTRIDE];
    float zz = __fmul_rn(z0, z0);
    zz = __fadd_rn(zz, __fmul_rn(z1, z1));
    zz = __fadd_rn(zz, __fmul_rn(z2, z2));
    zz = __fadd_rn(zz, __fmul_rn(z3, z3));

    __syncthreads();

    // lane c holds chunk c's max-dot; wave max-reduce
    float cm = sCm[lane][wid];
    float gmax = cm;
    #pragma unroll
    for (int off = 32; off; off >>= 1)
        gmax = fmaxf(gmax, __shfl_xor(gmax, off));

    // conservative bound (proven round 9): survivors have dot >= gmax - (2u + 1e-7)
    float u = __fmul_rn(__fadd_rn(zz, 0.01f), 2.38418579e-07f);   // (zz+.01)*2^-22
    float thr = __fsub_rn(gmax, __fadd_rn(__fadd_rn(u, u), 1e-7f));
    unsigned long long mask = __ballot(cm >= thr);   // wave-uniform, >=1 bit set

    // exact rescan of surviving chunks (coalesced: lane -> j0+lane, j0+64+lane)
    unsigned long long bkey = ~0ull;
    while (mask) {
        int c = __builtin_ctzll(mask);
        mask &= mask - 1ull;
        int j0 = c * CPC + lane;
        #pragma unroll
        for (int h = 0; h < 2; ++h) {
            int j = j0 + h * 64;
            float4 e = E[j];
            float ee = __fmul_rn(e.x, e.x);
            ee = __fadd_rn(ee, __fmul_rn(e.y, e.y));
            ee = __fadd_rn(ee, __fmul_rn(e.z, e.z));
            ee = __fadd_rn(ee, __fmul_rn(e.w, e.w));
            float dot = __fmul_rn(z0, e.x);
            dot = __fmaf_rn(z1, e.y, dot);
            dot = __fmaf_rn(z2, e.z, dot);
            dot = __fmaf_rn(z3, e.w, dot);
            float d = __fmaf_rn(-2.0f, dot, __fadd_rn(zz, ee));
            // key: (orderable d) << 32 | j  -> min key = min d, tie -> min j (first index)
            unsigned long long key =
                ((unsigned long long)fkey(d) << 32) | (unsigned int)j;
            bkey = key < bkey ? key : bkey;
        }
    }
    #pragma unroll
    for (int off = 32; off; off >>= 1) {
        unsigned long long o = __shfl_xor(bkey, off);
        bkey = o < bkey ? o : bkey;
    }
    int besti = (int)(unsigned int)(bkey & 0xFFFFFFFFull);

    if (lane == 0) {
        float4 e = E[besti];
        float* op = out + b * 16384 + hw;
        float t0 = __fsub_rn(e.x, z0);
        float t1 = __fsub_rn(e.y, z1);
        float t2 = __fsub_rn(e.z, z2);
        float t3 = __fsub_rn(e.w, z3);
        op[0]           = __fadd_rn(z0, t0);     // straight-through: z + (z_q - z)
        op[CSTRIDE]     = __fadd_rn(z1, t1);
        op[2 * CSTRIDE] = __fadd_rn(z2, t2);
        op[3 * CSTRIDE] = __fadd_rn(z3, t3);
        out[131073 + n] = (float)besti;          // indices as float32 (exact)
        double ds = (double)__fmul_rn(t0, t0) + (double)__fmul_rn(t1, t1)
                  + (double)__fmul_rn(t2, t2) + (double)__fmul_rn(t3, t3);
        sdata[wid] = ds;
    }
    __syncthreads();
    if (threadIdx.x == 0) {
        double s = 0.0;
        #pragma unroll
        for (int w = 0; w < RPB; ++w) s += sdata[w];
        partial[blockIdx.x] = s;                 // plain store: no coherence traffic
    }
}

// ---------------- kernel C: deterministic loss reduce (2048 partials)
__global__ void vq_loss_kernel(const double* __restrict__ partial, float* __restrict__ out) {
    __shared__ double sdata[256];
    int t = threadIdx.x;
    double s = 0.0;
    for (int i = t; i < 2048; i += 256) s += partial[i];
    sdata[t] = s;
    __syncthreads();
    #pragma unroll
    for (int st = 128; st > 0; st >>= 1) {
        if (t < st) sdata[t] += sdata[t + st];
        __syncthreads();
    }
    if (t == 0) {
        float m = (float)(sdata[0] / 131072.0);
        // loss = mean + BETA*mean (both means are numerically identical)
        out[131072] = __fadd_rn(m, __fmul_rn(0.25f, m));
    }
}

extern "C" void kernel_launch(void* const* d_in, const int* in_sizes, int n_in,
                              void* d_out, int out_size, void* d_ws, size_t ws_size,
                              hipStream_t stream) {
    const float* z = (const float*)d_in[0];
    const float4* E = (const float4*)d_in[1];
    float* out = (float*)d_out;

    char* ws = (char*)d_ws;
    float* cmaxb = (float*)ws;                                // 8 MB, [c][n]
    double* partial = (double*)(ws + (size_t)CH * N_POINTS * 4);   // 16 KB

    vq_filter_kernel<<<dim3(N_POINTS / (256 * PPT), CH), 256, 0, stream>>>(z, E, cmaxb);
    vq_resolve_kernel<<<RGRID, RB, 0, stream>>>(z, E, cmaxb, out, partial);
    vq_loss_kernel<<<1, 256, 0, stream>>>(partial, out);
}